// Round 10
// baseline (9478.886 us; speedup 1.0000x reference)
//
#include <hip/hip_runtime.h>

#define G 4                 // output points per workgroup
#define THREADS 256
#define IN_CH 32
#define KK 4
#define K3 64
#define CHUNK 128           // edges staged per A1/A2 round

// ---- W [2048][64] f32 -> transposed Wt [64][2048] f32 (d_ws) ----
__global__ __launch_bounds__(256) void wtrans_kernel(const float* __restrict__ W,
                                                     float* __restrict__ Wt) {
    const int idx = blockIdx.x * 256 + threadIdx.x;   // 0..131071
    if (idx >= 64 * 2048) return;
    const int o = idx >> 11;          // 0..63
    const int kidx = idx & 2047;      // 0..2047
    Wt[idx] = W[kidx * 64 + o];
}

template<int TRANS>
__global__ __launch_bounds__(THREADS, 4) void cconv_fused_kernel(
    const float* __restrict__ feats,
    const float* __restrict__ inp_points,
    const float* __restrict__ out_points,
    const float* __restrict__ out_extents,
    const float* __restrict__ scale_compat,
    const int*   __restrict__ nbr_index,
    const int*   __restrict__ row_splits,
    const float* __restrict__ nbr_dist,
    const float* __restrict__ Wmat,         // f32 [2048][64]
    const float* __restrict__ Wt,           // f32 [64][2048] (d_ws) if TRANS
    const float* __restrict__ bias,
    float* __restrict__ out,
    int n_out)
{
    __shared__ float A_s[G * K3 * IN_CH];        // 32 KB accumulator
    __shared__ float den_s[G];
    __shared__ int   rs_s[G + 1];
    __shared__ float opts_s[G * 3];
    __shared__ int   st_nbr[CHUNK];
    __shared__ float st_imp[CHUNK];
    __shared__ float st_frx[CHUNK];
    __shared__ float st_fry[CHUNK];
    __shared__ float st_frz[CHUNK];
    __shared__ int   st_bg[CHUNK];

    const int tid  = threadIdx.x;
    const int g0   = blockIdx.x * G;
    const int lane = tid & 63;

    {   // zero A_s: 2048 float4 / 256 thr = 8 each
        float4* A4z = (float4*)A_s;
        #pragma unroll
        for (int i = 0; i < 8; ++i)
            A4z[tid + i * THREADS] = make_float4(0.f, 0.f, 0.f, 0.f);
    }
    if (tid < G) den_s[tid] = 0.f;
    if (tid <= G) {
        int gg = g0 + tid;
        if (gg > n_out) gg = n_out;
        rs_s[tid] = row_splits[gg];
    }
    if (tid < G * 3) {
        int gg = g0 + tid / 3;
        opts_s[tid] = (gg < n_out) ? out_points[gg * 3 + tid % 3] : 0.f;
    }
    __syncthreads();

    const float inv_ext = 2.0f / out_extents[0];
    int rsl[G + 1];
    #pragma unroll
    for (int t = 0; t <= G; ++t) rsl[t] = rs_s[t];
    const int e0 = rsl[0], e1 = rsl[G];

    const int slot = tid >> 5;   // 0..7
    const int c    = tid & 31;   // channel lane

    for (int ch0 = e0; ch0 < e1; ch0 += CHUNK) {
        const int rem = e1 - ch0;
        const int nch = rem < CHUNK ? rem : CHUNK;

        // ---------- A1: one thread per edge, geometry once ----------
        int   eg   = -1;
        float eimp = 0.f;
        if (tid < nch) {
            const int   e   = ch0 + tid;
            const int   nbr = nbr_index[e];
            const float sc  = scale_compat[e];
            const float dd  = nbr_dist[e];
            float p = 1.f - dd * dd;
            p = p * p * p;
            p = fminf(fmaxf(p, 0.f), 1.f);
            const float imp = sc * p;

            int g = 0;
            #pragma unroll
            for (int t = 1; t < G; ++t) g += (e >= rsl[t]) ? 1 : 0;

            const float rx = (inp_points[nbr * 3 + 0] - opts_s[g * 3 + 0]) * inv_ext;
            const float ry = (inp_points[nbr * 3 + 1] - opts_s[g * 3 + 1]) * inv_ext;
            const float rz = (inp_points[nbr * 3 + 2] - opts_s[g * 3 + 2]) * inv_ext;

            const float r   = sqrtf(rx * rx + ry * ry + rz * rz);
            const float inf = fmaxf(fabsf(rx), fmaxf(fabsf(ry), fabsf(rz)));
            const float scl = (inf > 1e-8f) ? (r / fmaxf(inf, 1e-8f)) : 0.f;

            const float ux = fminf(fmaxf(rx * scl, -1.f), 1.f);
            const float uy = fminf(fmaxf(ry * scl, -1.f), 1.f);
            const float uz = fminf(fmaxf(rz * scl, -1.f), 1.f);

            const float tx = (ux + 1.f) * 1.5f;
            const float ty = (uy + 1.f) * 1.5f;
            const float tz = (uz + 1.f) * 1.5f;

            const float fx = fminf(fmaxf(floorf(tx), 0.f), 2.f);
            const float fy = fminf(fmaxf(floorf(ty), 0.f), 2.f);
            const float fz = fminf(fmaxf(floorf(tz), 0.f), 2.f);

            const float frx = tx - fx, fry = ty - fy, frz = tz - fz;
            const int ix = (int)fx, iy = (int)fy, iz = (int)fz;
            const int base = (ix * KK + iy) * KK + iz;

            st_nbr[tid] = nbr;
            st_imp[tid] = imp;
            st_frx[tid] = frx;
            st_fry[tid] = fry;
            st_frz[tid] = frz;
            st_bg[tid]  = base | (g << 8);
            eg = g; eimp = imp;
        }
        if (tid < CHUNK) {
            // segmented inclusive scan (edges g-sorted; idle lanes g=-1)
            #pragma unroll
            for (int d = 1; d < 64; d <<= 1) {
                const float oi = __shfl_up(eimp, d);
                const int   og = __shfl_up(eg, d);
                if (lane >= d && og == eg) eimp += oi;
            }
            const int gnext = __shfl_down(eg, 1);
            if (((lane == 63) || (gnext != eg)) && eg >= 0)
                atomicAdd(&den_s[eg], eimp);
        }
        __syncthreads();

        // ---------- A2: f32 scatter, 4-deep feats prefetch ----------
        #define SCAT(I, FV) { const int i = (I); if (i < nch) {               \
            const float imp = st_imp[i];                                      \
            const float frx = st_frx[i], fry = st_fry[i], frz = st_frz[i];    \
            const int bg = st_bg[i];                                          \
            const int g = bg >> 8; const int base = bg & 0xff;                \
            const float fwc = (FV) * imp;                                     \
            const float wx0 = 1.f - frx, wx1 = frx;                           \
            const float wy0 = 1.f - fry, wy1 = fry;                           \
            const float wz0 = 1.f - frz, wz1 = frz;                           \
            float* Ab = &A_s[(((g << 6) + base) << 5) + c]; float w;          \
            w = wx0 * wy0 * wz0; if (w > 0.f) atomicAdd(Ab + (0  << 5), fwc * w); \
            w = wx0 * wy0 * wz1; if (w > 0.f) atomicAdd(Ab + (1  << 5), fwc * w); \
            w = wx0 * wy1 * wz0; if (w > 0.f) atomicAdd(Ab + (4  << 5), fwc * w); \
            w = wx0 * wy1 * wz1; if (w > 0.f) atomicAdd(Ab + (5  << 5), fwc * w); \
            w = wx1 * wy0 * wz0; if (w > 0.f) atomicAdd(Ab + (16 << 5), fwc * w); \
            w = wx1 * wy0 * wz1; if (w > 0.f) atomicAdd(Ab + (17 << 5), fwc * w); \
            w = wx1 * wy1 * wz0; if (w > 0.f) atomicAdd(Ab + (20 << 5), fwc * w); \
            w = wx1 * wy1 * wz1; if (w > 0.f) atomicAdd(Ab + (21 << 5), fwc * w); } }

        float fv0, fv1, fv2, fv3;
        {
            const int i0 = slot, i1 = slot + 8, i2 = slot + 16, i3 = slot + 24;
            fv0 = (i0 < nch) ? feats[st_nbr[i0] * IN_CH + c] : 0.f;
            fv1 = (i1 < nch) ? feats[st_nbr[i1] * IN_CH + c] : 0.f;
            fv2 = (i2 < nch) ? feats[st_nbr[i2] * IN_CH + c] : 0.f;
            fv3 = (i3 < nch) ? feats[st_nbr[i3] * IN_CH + c] : 0.f;
        }
        for (int bi = 0; bi < nch; bi += 32) {
            const int ni = bi + 32;
            float nf0 = 0.f, nf1 = 0.f, nf2 = 0.f, nf3 = 0.f;
            if (ni < nch) {
                const int i0 = ni + slot, i1 = ni + slot + 8,
                          i2 = ni + slot + 16, i3 = ni + slot + 24;
                nf0 = (i0 < nch) ? feats[st_nbr[i0] * IN_CH + c] : 0.f;
                nf1 = (i1 < nch) ? feats[st_nbr[i1] * IN_CH + c] : 0.f;
                nf2 = (i2 < nch) ? feats[st_nbr[i2] * IN_CH + c] : 0.f;
                nf3 = (i3 < nch) ? feats[st_nbr[i3] * IN_CH + c] : 0.f;
            }
            SCAT(bi + slot,      fv0)
            SCAT(bi + slot + 8,  fv1)
            SCAT(bi + slot + 16, fv2)
            SCAT(bi + slot + 24, fv3)
            fv0 = nf0; fv1 = nf1; fv2 = nf2; fv3 = nf3;
        }
        #undef SCAT
        __syncthreads();
    }

    // ------- Phase B (dense, lockstep k=0..63, W double-buffered) -------
    // wave = point g; lane = (o4 = lane&15 -> outputs o4*4+j, i4 = lane>>4 -> channels i4*8..+7)
    const int wave = tid >> 6;   // g   (THREADS == 256 -> 4 waves)
    const int o4   = lane & 15;
    const int i4   = lane >> 4;

    float4 acc0 = make_float4(0.f, 0.f, 0.f, 0.f);
    float4 acc1 = make_float4(0.f, 0.f, 0.f, 0.f);
    float4 acc2 = make_float4(0.f, 0.f, 0.f, 0.f);
    float4 acc3 = make_float4(0.f, 0.f, 0.f, 0.f);

    const float* __restrict__ Ag = &A_s[(wave * K3) * IN_CH];
    const float4* __restrict__ W4 = (const float4*)Wmat;
    const float*  __restrict__ Wtb = Wt + (o4 * 4) * 2048 + (i4 << 3);  // TRANS base

    float4 wA[8];
    float4 wB[8];

    // TRANS: wP[2j],wP[2j+1] = channels i4*8..+7 of output o4*4+j, bin K
    #define LOADW(P, K) { if constexpr (TRANS) {                                \
            const float* p = Wtb + ((K) << 5);                                  \
            P[0] = *(const float4*)(p);        P[1] = *(const float4*)(p + 4);  \
            P[2] = *(const float4*)(p + 2048); P[3] = *(const float4*)(p + 2052);\
            P[4] = *(const float4*)(p + 4096); P[5] = *(const float4*)(p + 4100);\
            P[6] = *(const float4*)(p + 6144); P[7] = *(const float4*)(p + 6148);\
        } else {                                                                \
            const float4* Wk = &W4[(((K) << 5) + (i4 << 3)) * 16 + o4];         \
            P[0] = Wk[0];  P[1] = Wk[16]; P[2] = Wk[32]; P[3] = Wk[48];         \
            P[4] = Wk[64]; P[5] = Wk[80]; P[6] = Wk[96]; P[7] = Wk[112]; } }

    #define DOFMA(P, K) {                                                       \
        const float4 a0 = *(const float4*)&Ag[((K) << 5) + (i4 << 3)];          \
        const float4 a1 = *(const float4*)&Ag[((K) << 5) + (i4 << 3) + 4];      \
        if constexpr (TRANS) {                                                  \
            acc0.x = fmaf(a0.x, P[0].x, acc0.x); acc0.x = fmaf(a0.y, P[0].y, acc0.x); \
            acc0.x = fmaf(a0.z, P[0].z, acc0.x); acc0.x = fmaf(a0.w, P[0].w, acc0.x); \
            acc0.x = fmaf(a1.x, P[1].x, acc0.x); acc0.x = fmaf(a1.y, P[1].y, acc0.x); \
            acc0.x = fmaf(a1.z, P[1].z, acc0.x); acc0.x = fmaf(a1.w, P[1].w, acc0.x); \
            acc0.y = fmaf(a0.x, P[2].x, acc0.y); acc0.y = fmaf(a0.y, P[2].y, acc0.y); \
            acc0.y = fmaf(a0.z, P[2].z, acc0.y); acc0.y = fmaf(a0.w, P[2].w, acc0.y); \
            acc0.y = fmaf(a1.x, P[3].x, acc0.y); acc0.y = fmaf(a1.y, P[3].y, acc0.y); \
            acc0.y = fmaf(a1.z, P[3].z, acc0.y); acc0.y = fmaf(a1.w, P[3].w, acc0.y); \
            acc0.z = fmaf(a0.x, P[4].x, acc0.z); acc0.z = fmaf(a0.y, P[4].y, acc0.z); \
            acc0.z = fmaf(a0.z, P[4].z, acc0.z); acc0.z = fmaf(a0.w, P[4].w, acc0.z); \
            acc0.z = fmaf(a1.x, P[5].x, acc0.z); acc0.z = fmaf(a1.y, P[5].y, acc0.z); \
            acc0.z = fmaf(a1.z, P[5].z, acc0.z); acc0.z = fmaf(a1.w, P[5].w, acc0.z); \
            acc0.w = fmaf(a0.x, P[6].x, acc0.w); acc0.w = fmaf(a0.y, P[6].y, acc0.w); \
            acc0.w = fmaf(a0.z, P[6].z, acc0.w); acc0.w = fmaf(a0.w, P[6].w, acc0.w); \
            acc0.w = fmaf(a1.x, P[7].x, acc0.w); acc0.w = fmaf(a1.y, P[7].y, acc0.w); \
            acc0.w = fmaf(a1.z, P[7].z, acc0.w); acc0.w = fmaf(a1.w, P[7].w, acc0.w); \
        } else {                                                                \
            acc0.x = fmaf(a0.x, P[0].x, acc0.x); acc0.y = fmaf(a0.x, P[0].y, acc0.y); \
            acc0.z = fmaf(a0.x, P[0].z, acc0.z); acc0.w = fmaf(a0.x, P[0].w, acc0.w); \
            acc1.x = fmaf(a0.y, P[1].x, acc1.x); acc1.y = fmaf(a0.y, P[1].y, acc1.y); \
            acc1.z = fmaf(a0.y, P[1].z, acc1.z); acc1.w = fmaf(a0.y, P[1].w, acc1.w); \
            acc2.x = fmaf(a0.z, P[2].x, acc2.x); acc2.y = fmaf(a0.z, P[2].y, acc2.y); \
            acc2.z = fmaf(a0.z, P[2].z, acc2.z); acc2.w = fmaf(a0.z, P[2].w, acc2.w); \
            acc3.x = fmaf(a0.w, P[3].x, acc3.x); acc3.y = fmaf(a0.w, P[3].y, acc3.y); \
            acc3.z = fmaf(a0.w, P[3].z, acc3.z); acc3.w = fmaf(a0.w, P[3].w, acc3.w); \
            acc0.x = fmaf(a1.x, P[4].x, acc0.x); acc0.y = fmaf(a1.x, P[4].y, acc0.y); \
            acc0.z = fmaf(a1.x, P[4].z, acc0.z); acc0.w = fmaf(a1.x, P[4].w, acc0.w); \
            acc1.x = fmaf(a1.y, P[5].x, acc1.x); acc1.y = fmaf(a1.y, P[5].y, acc1.y); \
            acc1.z = fmaf(a1.y, P[5].z, acc1.z); acc1.w = fmaf(a1.y, P[5].w, acc1.w); \
            acc2.x = fmaf(a1.z, P[6].x, acc2.x); acc2.y = fmaf(a1.z, P[6].y, acc2.y); \
            acc2.z = fmaf(a1.z, P[6].z, acc2.z); acc2.w = fmaf(a1.z, P[6].w, acc2.w); \
            acc3.x = fmaf(a1.w, P[7].x, acc3.x); acc3.y = fmaf(a1.w, P[7].y, acc3.y); \
            acc3.z = fmaf(a1.w, P[7].z, acc3.z); acc3.w = fmaf(a1.w, P[7].w, acc3.w); } }

    LOADW(wA, 0)
    #pragma unroll 4
    for (int k = 0; k < K3; k += 2) {
        LOADW(wB, k + 1)
        DOFMA(wA, k)
        if (k + 2 < K3) LOADW(wA, k + 2)
        DOFMA(wB, k + 1)
    }
    #undef LOADW
    #undef DOFMA

    float4 t;
    if (TRANS) {
        t = acc0;                      // acc0 holds the 4 outputs directly
    } else {
        t.x = (acc0.x + acc1.x) + (acc2.x + acc3.x);
        t.y = (acc0.y + acc1.y) + (acc2.y + acc3.y);
        t.z = (acc0.z + acc1.z) + (acc2.z + acc3.z);
        t.w = (acc0.w + acc1.w) + (acc2.w + acc3.w);
    }

    // reduce across the 4 i4 channel-groups
    t.x += __shfl_xor(t.x, 16); t.y += __shfl_xor(t.y, 16);
    t.z += __shfl_xor(t.z, 16); t.w += __shfl_xor(t.w, 16);
    t.x += __shfl_xor(t.x, 32); t.y += __shfl_xor(t.y, 32);
    t.z += __shfl_xor(t.z, 32); t.w += __shfl_xor(t.w, 32);

    const int row = g0 + wave;
    if (lane < 16 && row < n_out) {
        float d = den_s[wave];
        d = (d != 0.f) ? d : 1.f;
        const float inv_d = 1.f / d;
        const float4 b4 = ((const float4*)bias)[o4];
        float4 y;
        y.x = fmaxf(t.x * inv_d + b4.x, 0.f);
        y.y = fmaxf(t.y * inv_d + b4.y, 0.f);
        y.z = fmaxf(t.z * inv_d + b4.z, 0.f);
        y.w = fmaxf(t.w * inv_d + b4.w, 0.f);
        ((float4*)out)[row * 16 + o4] = y;
    }
}

extern "C" void kernel_launch(void* const* d_in, const int* in_sizes, int n_in,
                              void* d_out, int out_size, void* d_ws, size_t ws_size,
                              hipStream_t stream) {
    const float* feats        = (const float*)d_in[0];
    const float* inp_points   = (const float*)d_in[1];
    const float* out_points   = (const float*)d_in[2];
    const float* out_extents  = (const float*)d_in[3];
    const float* scale_compat = (const float*)d_in[4];
    const int*   nbr_index    = (const int*)d_in[5];
    const int*   row_splits   = (const int*)d_in[6];
    const float* nbr_dist     = (const float*)d_in[7];
    const float* Wmat         = (const float*)d_in[8];
    const float* bias         = (const float*)d_in[9];
    float*       out          = (float*)d_out;
    float*       Wt           = (float*)d_ws;

    const int n_out = in_sizes[2] / 3;
    if (n_out <= 0) return;
    const int nwg = (n_out + G - 1) / G;
    const size_t wtBytes = (size_t)(K3 * IN_CH * 64) * sizeof(float);   // 512 KB

    if (ws_size >= wtBytes) {
        hipLaunchKernelGGL(wtrans_kernel, dim3((64 * 2048 + 255) / 256), dim3(256),
                           0, stream, Wmat, Wt);
        hipLaunchKernelGGL((cconv_fused_kernel<1>), dim3(nwg), dim3(THREADS), 0, stream,
                           feats, inp_points, out_points, out_extents, scale_compat,
                           nbr_index, row_splits, nbr_dist, Wmat, Wt, bias, out, n_out);
    } else {
        hipLaunchKernelGGL((cconv_fused_kernel<0>), dim3(nwg), dim3(THREADS), 0, stream,
                           feats, inp_points, out_points, out_extents, scale_compat,
                           nbr_index, row_splits, nbr_dist, Wmat, (const float*)nullptr,
                           bias, out, n_out);
    }
}

// Round 11
// 914.580 us; speedup vs baseline: 10.3642x; 10.3642x over previous
//
#include <hip/hip_runtime.h>

#define G 8                 // output points per workgroup
#define THREADS 512
#define IN_CH 32
#define KK 4
#define K3 64
#define CHUNK 256           // edges staged per A1/A2 round

// FULL=1: complete kernel, writes `out`.
// FULL=0: identical except the A2 scatter (feats gather + ds_atomic) is removed;
//         phase B runs on the zeroed accumulator with the REAL masks; result
//         checksum goes to ws (keeps everything live, never touches out).
template<int FULL>
__global__ __launch_bounds__(THREADS, 4) void cconv_kern(
    const float* __restrict__ feats,
    const float* __restrict__ inp_points,
    const float* __restrict__ out_points,
    const float* __restrict__ out_extents,
    const float* __restrict__ scale_compat,
    const int*   __restrict__ nbr_index,
    const int*   __restrict__ row_splits,
    const float* __restrict__ nbr_dist,
    const float* __restrict__ Wmat,         // f32 [2048][64]
    const float* __restrict__ bias,
    float* __restrict__ out,
    float* __restrict__ ws,                 // checksum sink (FULL=0)
    int n_out)
{
    __shared__ float A_s[G * K3 * IN_CH];        // 64 KB accumulator
    __shared__ float den_s[G];
    __shared__ unsigned int mask_s[G][2];
    __shared__ int   rs_s[G + 1];
    __shared__ float opts_s[G * 3];
    __shared__ int   st_nbr[CHUNK];
    __shared__ float st_imp[CHUNK];
    __shared__ float st_frx[CHUNK];
    __shared__ float st_fry[CHUNK];
    __shared__ float st_frz[CHUNK];
    __shared__ int   st_bg[CHUNK];

    const int tid  = threadIdx.x;
    const int g0   = blockIdx.x * G;
    const int lane = tid & 63;

    {
        float4* A4z = (float4*)A_s;
        #pragma unroll
        for (int i = 0; i < 8; ++i)
            A4z[tid + i * THREADS] = make_float4(0.f, 0.f, 0.f, 0.f);
    }
    if (tid < G) { den_s[tid] = 0.f; mask_s[tid][0] = 0u; mask_s[tid][1] = 0u; }
    if (tid <= G) {
        int gg = g0 + tid;
        if (gg > n_out) gg = n_out;
        rs_s[tid] = row_splits[gg];
    }
    if (tid < G * 3) {
        int gg = g0 + tid / 3;
        opts_s[tid] = (gg < n_out) ? out_points[gg * 3 + tid % 3] : 0.f;
    }
    __syncthreads();

    const float inv_ext = 2.0f / out_extents[0];
    int rsl[G + 1];
    #pragma unroll
    for (int t = 0; t <= G; ++t) rsl[t] = rs_s[t];
    const int e0 = rsl[0], e1 = rsl[G];

    const int slot = tid >> 5;   // 0..15
    const int c    = tid & 31;   // channel lane

    for (int ch0 = e0; ch0 < e1; ch0 += CHUNK) {
        const int rem = e1 - ch0;
        const int nch = rem < CHUNK ? rem : CHUNK;

        // ---------- A1: one thread per edge, geometry once ----------
        int          eg   = -1;
        float        eimp = 0.f;
        unsigned int em_lo = 0u, em_hi = 0u;
        if (tid < nch) {
            const int   e   = ch0 + tid;
            const int   nbr = nbr_index[e];
            const float sc  = scale_compat[e];
            const float dd  = nbr_dist[e];
            float p = 1.f - dd * dd;
            p = p * p * p;
            p = fminf(fmaxf(p, 0.f), 1.f);
            const float imp = sc * p;

            int g = 0;
            #pragma unroll
            for (int t = 1; t < G; ++t) g += (e >= rsl[t]) ? 1 : 0;

            const float rx = (inp_points[nbr * 3 + 0] - opts_s[g * 3 + 0]) * inv_ext;
            const float ry = (inp_points[nbr * 3 + 1] - opts_s[g * 3 + 1]) * inv_ext;
            const float rz = (inp_points[nbr * 3 + 2] - opts_s[g * 3 + 2]) * inv_ext;

            const float r   = sqrtf(rx * rx + ry * ry + rz * rz);
            const float inf = fmaxf(fabsf(rx), fmaxf(fabsf(ry), fabsf(rz)));
            const float scl = (inf > 1e-8f) ? (r / fmaxf(inf, 1e-8f)) : 0.f;

            const float ux = fminf(fmaxf(rx * scl, -1.f), 1.f);
            const float uy = fminf(fmaxf(ry * scl, -1.f), 1.f);
            const float uz = fminf(fmaxf(rz * scl, -1.f), 1.f);

            const float tx = (ux + 1.f) * 1.5f;
            const float ty = (uy + 1.f) * 1.5f;
            const float tz = (uz + 1.f) * 1.5f;

            const float fx = fminf(fmaxf(floorf(tx), 0.f), 2.f);
            const float fy = fminf(fmaxf(floorf(ty), 0.f), 2.f);
            const float fz = fminf(fmaxf(floorf(tz), 0.f), 2.f);

            const float frx = tx - fx, fry = ty - fy, frz = tz - fz;
            const int ix = (int)fx, iy = (int)fy, iz = (int)fz;
            const int base = (ix * KK + iy) * KK + iz;

            st_nbr[tid] = nbr;
            st_imp[tid] = imp;
            st_frx[tid] = frx;
            st_fry[tid] = fry;
            st_frz[tid] = frz;
            st_bg[tid]  = base | (g << 8);

            const float wx0 = 1.f - frx, wx1 = frx;
            const float wy0 = 1.f - fry, wy1 = fry;
            const float wz0 = 1.f - frz, wz1 = frz;
            #define MB(OFF, WV) { if ((WV) > 0.f) { const int k = base + (OFF); \
                if (k < 32) em_lo |= (1u << k); else em_hi |= (1u << (k - 32)); } }
            MB(0,  wx0 * wy0 * wz0) MB(1,  wx0 * wy0 * wz1)
            MB(4,  wx0 * wy1 * wz0) MB(5,  wx0 * wy1 * wz1)
            MB(16, wx1 * wy0 * wz0) MB(17, wx1 * wy0 * wz1)
            MB(20, wx1 * wy1 * wz0) MB(21, wx1 * wy1 * wz1)
            #undef MB
            eg = g; eimp = imp;
        }
        if (tid < CHUNK) {
            #pragma unroll
            for (int d = 1; d < 64; d <<= 1) {
                const float        oi = __shfl_up(eimp, d);
                const unsigned int ol = __shfl_up(em_lo, d);
                const unsigned int oh = __shfl_up(em_hi, d);
                const int          og = __shfl_up(eg, d);
                if (lane >= d && og == eg) { eimp += oi; em_lo |= ol; em_hi |= oh; }
            }
            const int gnext = __shfl_down(eg, 1);
            const bool tail = (lane == 63) || (gnext != eg);
            if (tail && eg >= 0) {
                atomicAdd(&den_s[eg], eimp);
                if (em_lo) atomicOr(&mask_s[eg][0], em_lo);
                if (em_hi) atomicOr(&mask_s[eg][1], em_hi);
            }
        }
        __syncthreads();

        // ---------- A2: f32 scatter, 4-deep feats prefetch (FULL only) ----------
        if constexpr (FULL) {
        #define SCAT(I, FV) { const int i = (I); if (i < nch) {               \
            const float imp = st_imp[i];                                      \
            const float frx = st_frx[i], fry = st_fry[i], frz = st_frz[i];    \
            const int bg = st_bg[i];                                          \
            const int g = bg >> 8; const int base = bg & 0xff;                \
            const float fwc = (FV) * imp;                                     \
            const float wx0 = 1.f - frx, wx1 = frx;                           \
            const float wy0 = 1.f - fry, wy1 = fry;                           \
            const float wz0 = 1.f - frz, wz1 = frz;                           \
            float* Ab = &A_s[(((g << 6) + base) << 5) + c]; float w;          \
            w = wx0 * wy0 * wz0; if (w > 0.f) atomicAdd(Ab + (0  << 5), fwc * w); \
            w = wx0 * wy0 * wz1; if (w > 0.f) atomicAdd(Ab + (1  << 5), fwc * w); \
            w = wx0 * wy1 * wz0; if (w > 0.f) atomicAdd(Ab + (4  << 5), fwc * w); \
            w = wx0 * wy1 * wz1; if (w > 0.f) atomicAdd(Ab + (5  << 5), fwc * w); \
            w = wx1 * wy0 * wz0; if (w > 0.f) atomicAdd(Ab + (16 << 5), fwc * w); \
            w = wx1 * wy0 * wz1; if (w > 0.f) atomicAdd(Ab + (17 << 5), fwc * w); \
            w = wx1 * wy1 * wz0; if (w > 0.f) atomicAdd(Ab + (20 << 5), fwc * w); \
            w = wx1 * wy1 * wz1; if (w > 0.f) atomicAdd(Ab + (21 << 5), fwc * w); } }

        float fv0, fv1, fv2, fv3;
        {
            const int i0 = slot, i1 = slot + 16, i2 = slot + 32, i3 = slot + 48;
            fv0 = (i0 < nch) ? feats[st_nbr[i0] * IN_CH + c] : 0.f;
            fv1 = (i1 < nch) ? feats[st_nbr[i1] * IN_CH + c] : 0.f;
            fv2 = (i2 < nch) ? feats[st_nbr[i2] * IN_CH + c] : 0.f;
            fv3 = (i3 < nch) ? feats[st_nbr[i3] * IN_CH + c] : 0.f;
        }
        for (int bi = 0; bi < nch; bi += 64) {
            const int ni = bi + 64;
            float nf0 = 0.f, nf1 = 0.f, nf2 = 0.f, nf3 = 0.f;
            if (ni < nch) {
                const int i0 = ni + slot, i1 = ni + slot + 16,
                          i2 = ni + slot + 32, i3 = ni + slot + 48;
                nf0 = (i0 < nch) ? feats[st_nbr[i0] * IN_CH + c] : 0.f;
                nf1 = (i1 < nch) ? feats[st_nbr[i1] * IN_CH + c] : 0.f;
                nf2 = (i2 < nch) ? feats[st_nbr[i2] * IN_CH + c] : 0.f;
                nf3 = (i3 < nch) ? feats[st_nbr[i3] * IN_CH + c] : 0.f;
            }
            SCAT(bi + slot,      fv0)
            SCAT(bi + slot + 16, fv1)
            SCAT(bi + slot + 32, fv2)
            SCAT(bi + slot + 48, fv3)
            fv0 = nf0; fv1 = nf1; fv2 = nf2; fv3 = nf3;
        }
        #undef SCAT
        }
        __syncthreads();
    }

    // ------- Phase B (sparse, W double-buffered) -------
    const int wave = tid >> 6;   // g
    const int o4   = lane & 15;
    const int i4   = lane >> 4;

    const unsigned int mlo = __builtin_amdgcn_readfirstlane(mask_s[wave][0]);
    const unsigned int mhi = __builtin_amdgcn_readfirstlane(mask_s[wave][1]);
    unsigned long long m = ((unsigned long long)mhi << 32) | mlo;

    float4 acc0 = make_float4(0.f, 0.f, 0.f, 0.f);
    float4 acc1 = make_float4(0.f, 0.f, 0.f, 0.f);
    float4 acc2 = make_float4(0.f, 0.f, 0.f, 0.f);
    float4 acc3 = make_float4(0.f, 0.f, 0.f, 0.f);

    const float4* __restrict__ W4 = (const float4*)Wmat;
    const float*  __restrict__ Ag = &A_s[(wave * K3) * IN_CH];

    float4 wA[8];
    float4 wB[8];

    #define LOADW(P, K) { const float4* Wk = &W4[(((K) << 5) + (i4 << 3)) * 16 + o4]; \
        P[0] = Wk[0];  P[1] = Wk[16]; P[2] = Wk[32]; P[3] = Wk[48];                    \
        P[4] = Wk[64]; P[5] = Wk[80]; P[6] = Wk[96]; P[7] = Wk[112]; }

    #define DOFMA(P, K) {                                                     \
        const float4 a0 = *(const float4*)&Ag[((K) << 5) + (i4 << 3)];        \
        const float4 a1 = *(const float4*)&Ag[((K) << 5) + (i4 << 3) + 4];    \
        acc0.x = fmaf(a0.x, P[0].x, acc0.x); acc0.y = fmaf(a0.x, P[0].y, acc0.y); \
        acc0.z = fmaf(a0.x, P[0].z, acc0.z); acc0.w = fmaf(a0.x, P[0].w, acc0.w); \
        acc1.x = fmaf(a0.y, P[1].x, acc1.x); acc1.y = fmaf(a0.y, P[1].y, acc1.y); \
        acc1.z = fmaf(a0.y, P[1].z, acc1.z); acc1.w = fmaf(a0.y, P[1].w, acc1.w); \
        acc2.x = fmaf(a0.z, P[2].x, acc2.x); acc2.y = fmaf(a0.z, P[2].y, acc2.y); \
        acc2.z = fmaf(a0.z, P[2].z, acc2.z); acc2.w = fmaf(a0.z, P[2].w, acc2.w); \
        acc3.x = fmaf(a0.w, P[3].x, acc3.x); acc3.y = fmaf(a0.w, P[3].y, acc3.y); \
        acc3.z = fmaf(a0.w, P[3].z, acc3.z); acc3.w = fmaf(a0.w, P[3].w, acc3.w); \
        acc0.x = fmaf(a1.x, P[4].x, acc0.x); acc0.y = fmaf(a1.x, P[4].y, acc0.y); \
        acc0.z = fmaf(a1.x, P[4].z, acc0.z); acc0.w = fmaf(a1.x, P[4].w, acc0.w); \
        acc1.x = fmaf(a1.y, P[5].x, acc1.x); acc1.y = fmaf(a1.y, P[5].y, acc1.y); \
        acc1.z = fmaf(a1.y, P[5].z, acc1.z); acc1.w = fmaf(a1.y, P[5].w, acc1.w); \
        acc2.x = fmaf(a1.z, P[6].x, acc2.x); acc2.y = fmaf(a1.z, P[6].y, acc2.y); \
        acc2.z = fmaf(a1.z, P[6].z, acc2.z); acc2.w = fmaf(a1.z, P[6].w, acc2.w); \
        acc3.x = fmaf(a1.w, P[7].x, acc3.x); acc3.y = fmaf(a1.w, P[7].y, acc3.y); \
        acc3.z = fmaf(a1.w, P[7].z, acc3.z); acc3.w = fmaf(a1.w, P[7].w, acc3.w); }

    int kA = -1, kB = -1;
    if (m) { kA = __ffsll(m) - 1; m &= m - 1; LOADW(wA, kA) }
    while (kA >= 0) {
        kB = -1;
        if (m) { kB = __ffsll(m) - 1; m &= m - 1; LOADW(wB, kB) }
        DOFMA(wA, kA)
        if (kB < 0) break;
        kA = -1;
        if (m) { kA = __ffsll(m) - 1; m &= m - 1; LOADW(wA, kA) }
        DOFMA(wB, kB)
    }
    #undef LOADW
    #undef DOFMA

    float4 t;
    t.x = (acc0.x + acc1.x) + (acc2.x + acc3.x);
    t.y = (acc0.y + acc1.y) + (acc2.y + acc3.y);
    t.z = (acc0.z + acc1.z) + (acc2.z + acc3.z);
    t.w = (acc0.w + acc1.w) + (acc2.w + acc3.w);

    t.x += __shfl_xor(t.x, 16); t.y += __shfl_xor(t.y, 16);
    t.z += __shfl_xor(t.z, 16); t.w += __shfl_xor(t.w, 16);
    t.x += __shfl_xor(t.x, 32); t.y += __shfl_xor(t.y, 32);
    t.z += __shfl_xor(t.z, 32); t.w += __shfl_xor(t.w, 32);

    const int row = g0 + wave;
    if constexpr (FULL) {
        if (lane < 16 && row < n_out) {
            float d = den_s[wave];
            d = (d != 0.f) ? d : 1.f;
            const float inv_d = 1.f / d;
            const float4 b4 = ((const float4*)bias)[o4];
            float4 y;
            y.x = fmaxf(t.x * inv_d + b4.x, 0.f);
            y.y = fmaxf(t.y * inv_d + b4.y, 0.f);
            y.z = fmaxf(t.z * inv_d + b4.z, 0.f);
            y.w = fmaxf(t.w * inv_d + b4.w, 0.f);
            ((float4*)out)[row * 16 + o4] = y;
        }
    } else {
        // checksum (keeps phase B + A1 stores live); never touches `out`
        float csum = t.x + t.y + t.z + t.w + den_s[wave];
        csum += (float)st_nbr[tid & (CHUNK - 1)];
        csum += st_imp[tid & (CHUNK - 1)] + st_frx[tid & (CHUNK - 1)];
        csum += st_fry[tid & (CHUNK - 1)] + st_frz[tid & (CHUNK - 1)];
        csum += (float)st_bg[tid & (CHUNK - 1)];
        if (lane == 0) ws[blockIdx.x * G + wave] = csum;
    }
}

extern "C" void kernel_launch(void* const* d_in, const int* in_sizes, int n_in,
                              void* d_out, int out_size, void* d_ws, size_t ws_size,
                              hipStream_t stream) {
    const float* feats        = (const float*)d_in[0];
    const float* inp_points   = (const float*)d_in[1];
    const float* out_points   = (const float*)d_in[2];
    const float* out_extents  = (const float*)d_in[3];
    const float* scale_compat = (const float*)d_in[4];
    const int*   nbr_index    = (const int*)d_in[5];
    const int*   row_splits   = (const int*)d_in[6];
    const float* nbr_dist     = (const float*)d_in[7];
    const float* Wmat         = (const float*)d_in[8];
    const float* bias         = (const float*)d_in[9];
    float*       out          = (float*)d_out;
    float*       ws           = (float*)d_ws;

    const int n_out = in_sizes[2] / 3;
    if (n_out <= 0) return;
    const int nwg = (n_out + G - 1) / G;

    // diagnostic dispatch (A2 scatter removed), only if scratch can hold checksums
    if (ws_size >= (size_t)nwg * G * sizeof(float)) {
        hipLaunchKernelGGL((cconv_kern<0>), dim3(nwg), dim3(THREADS), 0, stream,
                           feats, inp_points, out_points, out_extents, scale_compat,
                           nbr_index, row_splits, nbr_dist, Wmat, bias, out, ws, n_out);
    }
    // full kernel (correctness + baseline timing)
    hipLaunchKernelGGL((cconv_kern<1>), dim3(nwg), dim3(THREADS), 0, stream,
                       feats, inp_points, out_points, out_extents, scale_compat,
                       nbr_index, row_splits, nbr_dist, Wmat, bias, out, ws, n_out);
}

// Round 12
// 726.382 us; speedup vs baseline: 13.0495x; 1.2591x over previous
//
#include <hip/hip_runtime.h>

#define G 8                 // output points per workgroup
#define THREADS 512
#define IN_CH 32
#define KK 4
#define K3 64
#define CHUNK 256           // edges staged per A1/A2 round

__global__ __launch_bounds__(THREADS, 4) void cconv_kern(
    const float* __restrict__ feats,
    const float* __restrict__ inp_points,
    const float* __restrict__ out_points,
    const float* __restrict__ out_extents,
    const float* __restrict__ scale_compat,
    const int*   __restrict__ nbr_index,
    const int*   __restrict__ row_splits,
    const float* __restrict__ nbr_dist,
    const float* __restrict__ Wmat,         // f32 [2048][64]
    const float* __restrict__ bias,
    float* __restrict__ out,
    int n_out)
{
    __shared__ float A_s[G * K3 * IN_CH];        // 64 KB accumulator
    __shared__ float den_s[G];
    __shared__ unsigned int mask_s[G][2];
    __shared__ int   rs_s[G + 1];
    __shared__ float opts_s[G * 3];
    __shared__ float st_imp[CHUNK];
    __shared__ float st_frx[CHUNK];
    __shared__ float st_fry[CHUNK];
    __shared__ float st_frz[CHUNK];
    __shared__ int   st_bg[CHUNK];               // base | g<<8 | cmask<<16

    const int tid  = threadIdx.x;
    const int g0   = blockIdx.x * G;
    const int lane = tid & 63;

    {
        float4* A4z = (float4*)A_s;
        #pragma unroll
        for (int i = 0; i < 8; ++i)
            A4z[tid + i * THREADS] = make_float4(0.f, 0.f, 0.f, 0.f);
    }
    if (tid < G) { den_s[tid] = 0.f; mask_s[tid][0] = 0u; mask_s[tid][1] = 0u; }
    if (tid <= G) {
        int gg = g0 + tid;
        if (gg > n_out) gg = n_out;
        rs_s[tid] = row_splits[gg];
    }
    if (tid < G * 3) {
        int gg = g0 + tid / 3;
        opts_s[tid] = (gg < n_out) ? out_points[gg * 3 + tid % 3] : 0.f;
    }
    __syncthreads();

    const float inv_ext = 2.0f / out_extents[0];
    int rsl[G + 1];
    #pragma unroll
    for (int t = 0; t <= G; ++t) rsl[t] = rs_s[t];
    const int e0 = rsl[0], e1 = rsl[G];

    const int slot = tid >> 5;   // 0..15
    const int c    = tid & 31;   // channel lane

    for (int ch0 = e0; ch0 < e1; ch0 += CHUNK) {
        const int rem = e1 - ch0;
        const int nch = rem < CHUNK ? rem : CHUNK;

        // -------- feats gather prefetch for the WHOLE chunk (before A1) --------
        // thread's edges: i = slot + 16*m, m = 0..15; nbr read straight from global
        #define PREF(VAR, M) float VAR = 0.f; { const int i = slot + ((M) << 4);   \
            if (i < nch) { const int nb = nbr_index[ch0 + i];                      \
                           VAR = feats[nb * IN_CH + c]; } }
        PREF(f00, 0)  PREF(f01, 1)  PREF(f02, 2)  PREF(f03, 3)
        PREF(f04, 4)  PREF(f05, 5)  PREF(f06, 6)  PREF(f07, 7)
        PREF(f08, 8)  PREF(f09, 9)  PREF(f10, 10) PREF(f11, 11)
        PREF(f12, 12) PREF(f13, 13) PREF(f14, 14) PREF(f15, 15)
        #undef PREF

        // ---------- A1: one thread per edge, geometry once ----------
        int          eg   = -1;
        float        eimp = 0.f;
        unsigned int em_lo = 0u, em_hi = 0u;
        if (tid < nch) {
            const int   e   = ch0 + tid;
            const int   nbr = nbr_index[e];
            const float sc  = scale_compat[e];
            const float dd  = nbr_dist[e];
            float p = 1.f - dd * dd;
            p = p * p * p;
            p = fminf(fmaxf(p, 0.f), 1.f);
            const float imp = sc * p;

            int g = 0;
            #pragma unroll
            for (int t = 1; t < G; ++t) g += (e >= rsl[t]) ? 1 : 0;

            const float rx = (inp_points[nbr * 3 + 0] - opts_s[g * 3 + 0]) * inv_ext;
            const float ry = (inp_points[nbr * 3 + 1] - opts_s[g * 3 + 1]) * inv_ext;
            const float rz = (inp_points[nbr * 3 + 2] - opts_s[g * 3 + 2]) * inv_ext;

            const float r   = sqrtf(rx * rx + ry * ry + rz * rz);
            const float inf = fmaxf(fabsf(rx), fmaxf(fabsf(ry), fabsf(rz)));
            const float scl = (inf > 1e-8f) ? (r / fmaxf(inf, 1e-8f)) : 0.f;

            const float ux = fminf(fmaxf(rx * scl, -1.f), 1.f);
            const float uy = fminf(fmaxf(ry * scl, -1.f), 1.f);
            const float uz = fminf(fmaxf(rz * scl, -1.f), 1.f);

            const float tx = (ux + 1.f) * 1.5f;
            const float ty = (uy + 1.f) * 1.5f;
            const float tz = (uz + 1.f) * 1.5f;

            const float fx = fminf(fmaxf(floorf(tx), 0.f), 2.f);
            const float fy = fminf(fmaxf(floorf(ty), 0.f), 2.f);
            const float fz = fminf(fmaxf(floorf(tz), 0.f), 2.f);

            const float frx = tx - fx, fry = ty - fy, frz = tz - fz;
            const int ix = (int)fx, iy = (int)fy, iz = (int)fz;
            const int base = (ix * KK + iy) * KK + iz;

            const float wx0 = 1.f - frx, wx1 = frx;
            const float wy0 = 1.f - fry, wy1 = fry;
            const float wz0 = 1.f - frz, wz1 = frz;

            int cmask = 0;
            // corner j: bits (dx,dy,dz) = (j>>2, (j>>1)&1, j&1); bin offset dx*16+dy*4+dz
            #define MB(J, OFF, WV) { if ((WV) > 0.f) { cmask |= (1 << (J));      \
                const int k = base + (OFF);                                      \
                if (k < 32) em_lo |= (1u << k); else em_hi |= (1u << (k - 32)); } }
            MB(0, 0,  wx0 * wy0 * wz0) MB(1, 1,  wx0 * wy0 * wz1)
            MB(2, 4,  wx0 * wy1 * wz0) MB(3, 5,  wx0 * wy1 * wz1)
            MB(4, 16, wx1 * wy0 * wz0) MB(5, 17, wx1 * wy0 * wz1)
            MB(6, 20, wx1 * wy1 * wz0) MB(7, 21, wx1 * wy1 * wz1)
            #undef MB

            st_imp[tid] = imp;
            st_frx[tid] = frx;
            st_fry[tid] = fry;
            st_frz[tid] = frz;
            st_bg[tid]  = base | (g << 8) | (cmask << 16);
            eg = g; eimp = imp;
        }
        if (tid < CHUNK) {
            // segmented inclusive scan (edges g-sorted; idle lanes g=-1)
            #pragma unroll
            for (int d = 1; d < 64; d <<= 1) {
                const float        oi = __shfl_up(eimp, d);
                const unsigned int ol = __shfl_up(em_lo, d);
                const unsigned int oh = __shfl_up(em_hi, d);
                const int          og = __shfl_up(eg, d);
                if (lane >= d && og == eg) { eimp += oi; em_lo |= ol; em_hi |= oh; }
            }
            const int gnext = __shfl_down(eg, 1);
            const bool tail = (lane == 63) || (gnext != eg);
            if (tail && eg >= 0) {
                atomicAdd(&den_s[eg], eimp);
                if (em_lo) atomicOr(&mask_s[eg][0], em_lo);
                if (em_hi) atomicOr(&mask_s[eg][1], em_hi);
            }
        }
        __syncthreads();

        // ---------- A2: cmask-compressed scatter (only active corners) ----------
        #define SCAT(M, FV) { const int i = slot + ((M) << 4); if (i < nch) {     \
            const float imp = st_imp[i];                                          \
            const float frx = st_frx[i], fry = st_fry[i], frz = st_frz[i];        \
            const int bg = st_bg[i];                                              \
            const int g = (bg >> 8) & 0xff; const int base = bg & 0xff;           \
            int cm = (bg >> 16) & 0xff;                                           \
            const float fwc = (FV) * imp;                                         \
            const float wx0 = 1.f - frx, wx1 = frx;                               \
            const float wy0 = 1.f - fry, wy1 = fry;                               \
            const float wz0 = 1.f - frz, wz1 = frz;                               \
            float* Ab = &A_s[(((g << 6) + base) << 5) + c];                       \
            while (cm) {                                                          \
                const int j = __ffs(cm) - 1; cm &= cm - 1;                        \
                const float w = ((j & 4) ? wx1 : wx0) *                           \
                                ((j & 2) ? wy1 : wy0) *                           \
                                ((j & 1) ? wz1 : wz0);                            \
                const int off = ((j & 4) << 2) | ((j & 2) << 1) | (j & 1);        \
                atomicAdd(Ab + (off << 5), fwc * w);                              \
            } } }
        SCAT(0,  f00) SCAT(1,  f01) SCAT(2,  f02) SCAT(3,  f03)
        SCAT(4,  f04) SCAT(5,  f05) SCAT(6,  f06) SCAT(7,  f07)
        SCAT(8,  f08) SCAT(9,  f09) SCAT(10, f10) SCAT(11, f11)
        SCAT(12, f12) SCAT(13, f13) SCAT(14, f14) SCAT(15, f15)
        #undef SCAT
        __syncthreads();
    }

    // ------- Phase B (sparse, W double-buffered) -------
    const int wave = tid >> 6;   // g
    const int o4   = lane & 15;
    const int i4   = lane >> 4;

    const unsigned int mlo = __builtin_amdgcn_readfirstlane(mask_s[wave][0]);
    const unsigned int mhi = __builtin_amdgcn_readfirstlane(mask_s[wave][1]);
    unsigned long long m = ((unsigned long long)mhi << 32) | mlo;

    float4 acc0 = make_float4(0.f, 0.f, 0.f, 0.f);
    float4 acc1 = make_float4(0.f, 0.f, 0.f, 0.f);
    float4 acc2 = make_float4(0.f, 0.f, 0.f, 0.f);
    float4 acc3 = make_float4(0.f, 0.f, 0.f, 0.f);

    const float4* __restrict__ W4 = (const float4*)Wmat;
    const float*  __restrict__ Ag = &A_s[(wave * K3) * IN_CH];

    float4 wA[8];
    float4 wB[8];

    #define LOADW(P, K) { const float4* Wk = &W4[(((K) << 5) + (i4 << 3)) * 16 + o4]; \
        P[0] = Wk[0];  P[1] = Wk[16]; P[2] = Wk[32]; P[3] = Wk[48];                    \
        P[4] = Wk[64]; P[5] = Wk[80]; P[6] = Wk[96]; P[7] = Wk[112]; }

    #define DOFMA(P, K) {                                                     \
        const float4 a0 = *(const float4*)&Ag[((K) << 5) + (i4 << 3)];        \
        const float4 a1 = *(const float4*)&Ag[((K) << 5) + (i4 << 3) + 4];    \
        acc0.x = fmaf(a0.x, P[0].x, acc0.x); acc0.y = fmaf(a0.x, P[0].y, acc0.y); \
        acc0.z = fmaf(a0.x, P[0].z, acc0.z); acc0.w = fmaf(a0.x, P[0].w, acc0.w); \
        acc1.x = fmaf(a0.y, P[1].x, acc1.x); acc1.y = fmaf(a0.y, P[1].y, acc1.y); \
        acc1.z = fmaf(a0.y, P[1].z, acc1.z); acc1.w = fmaf(a0.y, P[1].w, acc1.w); \
        acc2.x = fmaf(a0.z, P[2].x, acc2.x); acc2.y = fmaf(a0.z, P[2].y, acc2.y); \
        acc2.z = fmaf(a0.z, P[2].z, acc2.z); acc2.w = fmaf(a0.z, P[2].w, acc2.w); \
        acc3.x = fmaf(a0.w, P[3].x, acc3.x); acc3.y = fmaf(a0.w, P[3].y, acc3.y); \
        acc3.z = fmaf(a0.w, P[3].z, acc3.z); acc3.w = fmaf(a0.w, P[3].w, acc3.w); \
        acc0.x = fmaf(a1.x, P[4].x, acc0.x); acc0.y = fmaf(a1.x, P[4].y, acc0.y); \
        acc0.z = fmaf(a1.x, P[4].z, acc0.z); acc0.w = fmaf(a1.x, P[4].w, acc0.w); \
        acc1.x = fmaf(a1.y, P[5].x, acc1.x); acc1.y = fmaf(a1.y, P[5].y, acc1.y); \
        acc1.z = fmaf(a1.y, P[5].z, acc1.z); acc1.w = fmaf(a1.y, P[5].w, acc1.w); \
        acc2.x = fmaf(a1.z, P[6].x, acc2.x); acc2.y = fmaf(a1.z, P[6].y, acc2.y); \
        acc2.z = fmaf(a1.z, P[6].z, acc2.z); acc2.w = fmaf(a1.z, P[6].w, acc2.w); \
        acc3.x = fmaf(a1.w, P[7].x, acc3.x); acc3.y = fmaf(a1.w, P[7].y, acc3.y); \
        acc3.z = fmaf(a1.w, P[7].z, acc3.z); acc3.w = fmaf(a1.w, P[7].w, acc3.w); }

    int kA = -1, kB = -1;
    if (m) { kA = __ffsll(m) - 1; m &= m - 1; LOADW(wA, kA) }
    while (kA >= 0) {
        kB = -1;
        if (m) { kB = __ffsll(m) - 1; m &= m - 1; LOADW(wB, kB) }
        DOFMA(wA, kA)
        if (kB < 0) break;
        kA = -1;
        if (m) { kA = __ffsll(m) - 1; m &= m - 1; LOADW(wA, kA) }
        DOFMA(wB, kB)
    }
    #undef LOADW
    #undef DOFMA

    float4 t;
    t.x = (acc0.x + acc1.x) + (acc2.x + acc3.x);
    t.y = (acc0.y + acc1.y) + (acc2.y + acc3.y);
    t.z = (acc0.z + acc1.z) + (acc2.z + acc3.z);
    t.w = (acc0.w + acc1.w) + (acc2.w + acc3.w);

    t.x += __shfl_xor(t.x, 16); t.y += __shfl_xor(t.y, 16);
    t.z += __shfl_xor(t.z, 16); t.w += __shfl_xor(t.w, 16);
    t.x += __shfl_xor(t.x, 32); t.y += __shfl_xor(t.y, 32);
    t.z += __shfl_xor(t.z, 32); t.w += __shfl_xor(t.w, 32);

    const int row = g0 + wave;
    if (lane < 16 && row < n_out) {
        float d = den_s[wave];
        d = (d != 0.f) ? d : 1.f;
        const float inv_d = 1.f / d;
        const float4 b4 = ((const float4*)bias)[o4];
        float4 y;
        y.x = fmaxf(t.x * inv_d + b4.x, 0.f);
        y.y = fmaxf(t.y * inv_d + b4.y, 0.f);
        y.z = fmaxf(t.z * inv_d + b4.z, 0.f);
        y.w = fmaxf(t.w * inv_d + b4.w, 0.f);
        ((float4*)out)[row * 16 + o4] = y;
    }
}

extern "C" void kernel_launch(void* const* d_in, const int* in_sizes, int n_in,
                              void* d_out, int out_size, void* d_ws, size_t ws_size,
                              hipStream_t stream) {
    const float* feats        = (const float*)d_in[0];
    const float* inp_points   = (const float*)d_in[1];
    const float* out_points   = (const float*)d_in[2];
    const float* out_extents  = (const float*)d_in[3];
    const float* scale_compat = (const float*)d_in[4];
    const int*   nbr_index    = (const int*)d_in[5];
    const int*   row_splits   = (const int*)d_in[6];
    const float* nbr_dist     = (const float*)d_in[7];
    const float* Wmat         = (const float*)d_in[8];
    const float* bias         = (const float*)d_in[9];
    float*       out          = (float*)d_out;

    const int n_out = in_sizes[2] / 3;
    if (n_out <= 0) return;
    const int nwg = (n_out + G - 1) / G;

    hipLaunchKernelGGL(cconv_kern, dim3(nwg), dim3(THREADS), 0, stream,
                       feats, inp_points, out_points, out_extents, scale_compat,
                       nbr_index, row_splits, nbr_dist, Wmat, bias, out, n_out);
}

// Round 13
// 694.551 us; speedup vs baseline: 13.6475x; 1.0458x over previous
//
#include <hip/hip_runtime.h>

#define G 4                 // output points per workgroup
#define THREADS 512
#define IN_CH 32
#define KK 4
#define K3 64
#define CHUNK 256           // edges staged per A1/A2 round

__global__ __launch_bounds__(THREADS, 4) void cconv_kern(
    const float* __restrict__ feats,
    const float* __restrict__ inp_points,
    const float* __restrict__ out_points,
    const float* __restrict__ out_extents,
    const float* __restrict__ scale_compat,
    const int*   __restrict__ nbr_index,
    const int*   __restrict__ row_splits,
    const float* __restrict__ nbr_dist,
    const float* __restrict__ Wmat,         // f32 [2048][64]
    const float* __restrict__ bias,
    float* __restrict__ out,
    int n_out)
{
    __shared__ float A_s[G * K3 * IN_CH];        // 32 KB accumulator
    __shared__ float den_s[G];
    __shared__ unsigned int mask_s[G][2];
    __shared__ int   rs_s[G + 1];
    __shared__ float opts_s[G * 3];
    __shared__ int   st_nbr[CHUNK];
    __shared__ float st_f[4 * CHUNK];            // imp|frx|fry|frz; reused as red[8][64]
    __shared__ int   st_bg[CHUNK];               // base | (g<<8)

    float* const st_imp = st_f;
    float* const st_frx = st_f + CHUNK;
    float* const st_fry = st_f + 2 * CHUNK;
    float* const st_frz = st_f + 3 * CHUNK;

    const int tid  = threadIdx.x;
    const int g0   = blockIdx.x * G;
    const int lane = tid & 63;

    {   // zero A_s: 2048 float4 / 512 threads = 4 each
        float4* A4z = (float4*)A_s;
        #pragma unroll
        for (int i = 0; i < 4; ++i)
            A4z[tid + i * THREADS] = make_float4(0.f, 0.f, 0.f, 0.f);
    }
    if (tid < G) { den_s[tid] = 0.f; mask_s[tid][0] = 0u; mask_s[tid][1] = 0u; }
    if (tid <= G) {
        int gg = g0 + tid;
        if (gg > n_out) gg = n_out;
        rs_s[tid] = row_splits[gg];
    }
    if (tid < G * 3) {
        int gg = g0 + tid / 3;
        opts_s[tid] = (gg < n_out) ? out_points[gg * 3 + tid % 3] : 0.f;
    }
    __syncthreads();

    const float inv_ext = 2.0f / out_extents[0];
    int rsl[G + 1];
    #pragma unroll
    for (int t = 0; t <= G; ++t) rsl[t] = rs_s[t];
    const int e0 = rsl[0], e1 = rsl[G];

    const int slot = tid >> 5;   // 0..15
    const int c    = tid & 31;   // channel lane

    for (int ch0 = e0; ch0 < e1; ch0 += CHUNK) {
        const int rem = e1 - ch0;
        const int nch = rem < CHUNK ? rem : CHUNK;

        // ---------- A1: one thread per edge, geometry once ----------
        int          eg   = -1;
        float        eimp = 0.f;
        unsigned int em_lo = 0u, em_hi = 0u;
        if (tid < nch) {
            const int   e   = ch0 + tid;
            const int   nbr = nbr_index[e];
            const float sc  = scale_compat[e];
            const float dd  = nbr_dist[e];
            float p = 1.f - dd * dd;
            p = p * p * p;
            p = fminf(fmaxf(p, 0.f), 1.f);
            const float imp = sc * p;

            int g = 0;
            #pragma unroll
            for (int t = 1; t < G; ++t) g += (e >= rsl[t]) ? 1 : 0;

            const float rx = (inp_points[nbr * 3 + 0] - opts_s[g * 3 + 0]) * inv_ext;
            const float ry = (inp_points[nbr * 3 + 1] - opts_s[g * 3 + 1]) * inv_ext;
            const float rz = (inp_points[nbr * 3 + 2] - opts_s[g * 3 + 2]) * inv_ext;

            const float r   = sqrtf(rx * rx + ry * ry + rz * rz);
            const float inf = fmaxf(fabsf(rx), fmaxf(fabsf(ry), fabsf(rz)));
            const float scl = (inf > 1e-8f) ? (r / fmaxf(inf, 1e-8f)) : 0.f;

            const float ux = fminf(fmaxf(rx * scl, -1.f), 1.f);
            const float uy = fminf(fmaxf(ry * scl, -1.f), 1.f);
            const float uz = fminf(fmaxf(rz * scl, -1.f), 1.f);

            const float tx = (ux + 1.f) * 1.5f;
            const float ty = (uy + 1.f) * 1.5f;
            const float tz = (uz + 1.f) * 1.5f;

            const float fx = fminf(fmaxf(floorf(tx), 0.f), 2.f);
            const float fy = fminf(fmaxf(floorf(ty), 0.f), 2.f);
            const float fz = fminf(fmaxf(floorf(tz), 0.f), 2.f);

            const float frx = tx - fx, fry = ty - fy, frz = tz - fz;
            const int ix = (int)fx, iy = (int)fy, iz = (int)fz;
            const int base = (ix * KK + iy) * KK + iz;

            st_nbr[tid] = nbr;
            st_imp[tid] = imp;
            st_frx[tid] = frx;
            st_fry[tid] = fry;
            st_frz[tid] = frz;
            st_bg[tid]  = base | (g << 8);

            const float wx0 = 1.f - frx, wx1 = frx;
            const float wy0 = 1.f - fry, wy1 = fry;
            const float wz0 = 1.f - frz, wz1 = frz;
            #define MB(OFF, WV) { if ((WV) > 0.f) { const int k = base + (OFF); \
                if (k < 32) em_lo |= (1u << k); else em_hi |= (1u << (k - 32)); } }
            MB(0,  wx0 * wy0 * wz0) MB(1,  wx0 * wy0 * wz1)
            MB(4,  wx0 * wy1 * wz0) MB(5,  wx0 * wy1 * wz1)
            MB(16, wx1 * wy0 * wz0) MB(17, wx1 * wy0 * wz1)
            MB(20, wx1 * wy1 * wz0) MB(21, wx1 * wy1 * wz1)
            #undef MB
            eg = g; eimp = imp;
        }
        if (tid < CHUNK) {
            // segmented inclusive scan (edges g-sorted; idle lanes g=-1)
            #pragma unroll
            for (int d = 1; d < 64; d <<= 1) {
                const float        oi = __shfl_up(eimp, d);
                const unsigned int ol = __shfl_up(em_lo, d);
                const unsigned int oh = __shfl_up(em_hi, d);
                const int          og = __shfl_up(eg, d);
                if (lane >= d && og == eg) { eimp += oi; em_lo |= ol; em_hi |= oh; }
            }
            const int gnext = __shfl_down(eg, 1);
            const bool tail = (lane == 63) || (gnext != eg);
            if (tail && eg >= 0) {
                atomicAdd(&den_s[eg], eimp);
                if (em_lo) atomicOr(&mask_s[eg][0], em_lo);
                if (em_hi) atomicOr(&mask_s[eg][1], em_hi);
            }
        }
        __syncthreads();

        // ---------- A2: f32 scatter, 4-deep feats prefetch (r5 pattern) ----------
        #define SCAT(I, FV) { const int i = (I); if (i < nch) {               \
            const float imp = st_imp[i];                                      \
            const float frx = st_frx[i], fry = st_fry[i], frz = st_frz[i];    \
            const int bg = st_bg[i];                                          \
            const int g = bg >> 8; const int base = bg & 0xff;                \
            const float fwc = (FV) * imp;                                     \
            const float wx0 = 1.f - frx, wx1 = frx;                           \
            const float wy0 = 1.f - fry, wy1 = fry;                           \
            const float wz0 = 1.f - frz, wz1 = frz;                           \
            float* Ab = &A_s[(((g << 6) + base) << 5) + c]; float w;          \
            w = wx0 * wy0 * wz0; if (w > 0.f) atomicAdd(Ab + (0  << 5), fwc * w); \
            w = wx0 * wy0 * wz1; if (w > 0.f) atomicAdd(Ab + (1  << 5), fwc * w); \
            w = wx0 * wy1 * wz0; if (w > 0.f) atomicAdd(Ab + (4  << 5), fwc * w); \
            w = wx0 * wy1 * wz1; if (w > 0.f) atomicAdd(Ab + (5  << 5), fwc * w); \
            w = wx1 * wy0 * wz0; if (w > 0.f) atomicAdd(Ab + (16 << 5), fwc * w); \
            w = wx1 * wy0 * wz1; if (w > 0.f) atomicAdd(Ab + (17 << 5), fwc * w); \
            w = wx1 * wy1 * wz0; if (w > 0.f) atomicAdd(Ab + (20 << 5), fwc * w); \
            w = wx1 * wy1 * wz1; if (w > 0.f) atomicAdd(Ab + (21 << 5), fwc * w); } }

        float fv0, fv1, fv2, fv3;
        {
            const int i0 = slot, i1 = slot + 16, i2 = slot + 32, i3 = slot + 48;
            fv0 = (i0 < nch) ? feats[st_nbr[i0] * IN_CH + c] : 0.f;
            fv1 = (i1 < nch) ? feats[st_nbr[i1] * IN_CH + c] : 0.f;
            fv2 = (i2 < nch) ? feats[st_nbr[i2] * IN_CH + c] : 0.f;
            fv3 = (i3 < nch) ? feats[st_nbr[i3] * IN_CH + c] : 0.f;
        }
        for (int bi = 0; bi < nch; bi += 64) {
            const int ni = bi + 64;
            float nf0 = 0.f, nf1 = 0.f, nf2 = 0.f, nf3 = 0.f;
            if (ni < nch) {
                const int i0 = ni + slot, i1 = ni + slot + 16,
                          i2 = ni + slot + 32, i3 = ni + slot + 48;
                nf0 = (i0 < nch) ? feats[st_nbr[i0] * IN_CH + c] : 0.f;
                nf1 = (i1 < nch) ? feats[st_nbr[i1] * IN_CH + c] : 0.f;
                nf2 = (i2 < nch) ? feats[st_nbr[i2] * IN_CH + c] : 0.f;
                nf3 = (i3 < nch) ? feats[st_nbr[i3] * IN_CH + c] : 0.f;
            }
            SCAT(bi + slot,      fv0)
            SCAT(bi + slot + 16, fv1)
            SCAT(bi + slot + 32, fv2)
            SCAT(bi + slot + 48, fv3)
            fv0 = nf0; fv1 = nf1; fv2 = nf2; fv3 = nf3;
        }
        #undef SCAT
        __syncthreads();
    }

    // ------- Phase B: wave-pair per point; wave h handles mask half h -------
    const int w   = tid >> 6;    // 0..7
    const int pg  = w >> 1;      // point 0..3
    const int h   = w & 1;       // k-half
    const int o4  = lane & 15;
    const int i4  = lane >> 4;

    unsigned int m32 = __builtin_amdgcn_readfirstlane(mask_s[pg][h]);
    const int kofs = h << 5;

    float4 acc0 = make_float4(0.f, 0.f, 0.f, 0.f);
    float4 acc1 = make_float4(0.f, 0.f, 0.f, 0.f);
    float4 acc2 = make_float4(0.f, 0.f, 0.f, 0.f);
    float4 acc3 = make_float4(0.f, 0.f, 0.f, 0.f);

    const float4* __restrict__ W4 = (const float4*)Wmat;
    const float*  __restrict__ Ag = &A_s[(pg * K3) * IN_CH];

    float4 wA[8];
    float4 wB[8];

    #define LOADW(P, K) { const float4* Wk = &W4[(((K) << 5) + (i4 << 3)) * 16 + o4]; \
        P[0] = Wk[0];  P[1] = Wk[16]; P[2] = Wk[32]; P[3] = Wk[48];                    \
        P[4] = Wk[64]; P[5] = Wk[80]; P[6] = Wk[96]; P[7] = Wk[112]; }

    #define DOFMA(P, K) {                                                     \
        const float4 a0 = *(const float4*)&Ag[((K) << 5) + (i4 << 3)];        \
        const float4 a1 = *(const float4*)&Ag[((K) << 5) + (i4 << 3) + 4];    \
        acc0.x = fmaf(a0.x, P[0].x, acc0.x); acc0.y = fmaf(a0.x, P[0].y, acc0.y); \
        acc0.z = fmaf(a0.x, P[0].z, acc0.z); acc0.w = fmaf(a0.x, P[0].w, acc0.w); \
        acc1.x = fmaf(a0.y, P[1].x, acc1.x); acc1.y = fmaf(a0.y, P[1].y, acc1.y); \
        acc1.z = fmaf(a0.y, P[1].z, acc1.z); acc1.w = fmaf(a0.y, P[1].w, acc1.w); \
        acc2.x = fmaf(a0.z, P[2].x, acc2.x); acc2.y = fmaf(a0.z, P[2].y, acc2.y); \
        acc2.z = fmaf(a0.z, P[2].z, acc2.z); acc2.w = fmaf(a0.z, P[2].w, acc2.w); \
        acc3.x = fmaf(a0.w, P[3].x, acc3.x); acc3.y = fmaf(a0.w, P[3].y, acc3.y); \
        acc3.z = fmaf(a0.w, P[3].z, acc3.z); acc3.w = fmaf(a0.w, P[3].w, acc3.w); \
        acc0.x = fmaf(a1.x, P[4].x, acc0.x); acc0.y = fmaf(a1.x, P[4].y, acc0.y); \
        acc0.z = fmaf(a1.x, P[4].z, acc0.z); acc0.w = fmaf(a1.x, P[4].w, acc0.w); \
        acc1.x = fmaf(a1.y, P[5].x, acc1.x); acc1.y = fmaf(a1.y, P[5].y, acc1.y); \
        acc1.z = fmaf(a1.y, P[5].z, acc1.z); acc1.w = fmaf(a1.y, P[5].w, acc1.w); \
        acc2.x = fmaf(a1.z, P[6].x, acc2.x); acc2.y = fmaf(a1.z, P[6].y, acc2.y); \
        acc2.z = fmaf(a1.z, P[6].z, acc2.z); acc2.w = fmaf(a1.z, P[6].w, acc2.w); \
        acc3.x = fmaf(a1.w, P[7].x, acc3.x); acc3.y = fmaf(a1.w, P[7].y, acc3.y); \
        acc3.z = fmaf(a1.w, P[7].z, acc3.z); acc3.w = fmaf(a1.w, P[7].w, acc3.w); }

    int kA = -1, kB = -1;
    if (m32) { kA = (__ffs(m32) - 1) + kofs; m32 &= m32 - 1; LOADW(wA, kA) }
    while (kA >= 0) {
        kB = -1;
        if (m32) { kB = (__ffs(m32) - 1) + kofs; m32 &= m32 - 1; LOADW(wB, kB) }
        DOFMA(wA, kA)
        if (kB < 0) break;
        kA = -1;
        if (m32) { kA = (__ffs(m32) - 1) + kofs; m32 &= m32 - 1; LOADW(wA, kA) }
        DOFMA(wB, kB)
    }
    #undef LOADW
    #undef DOFMA

    float4 t;
    t.x = (acc0.x + acc1.x) + (acc2.x + acc3.x);
    t.y = (acc0.y + acc1.y) + (acc2.y + acc3.y);
    t.z = (acc0.z + acc1.z) + (acc2.z + acc3.z);
    t.w = (acc0.w + acc1.w) + (acc2.w + acc3.w);

    // reduce across the 4 i4 channel-groups
    t.x += __shfl_xor(t.x, 16); t.y += __shfl_xor(t.y, 16);
    t.z += __shfl_xor(t.z, 16); t.w += __shfl_xor(t.w, 16);
    t.x += __shfl_xor(t.x, 32); t.y += __shfl_xor(t.y, 32);
    t.z += __shfl_xor(t.z, 32); t.w += __shfl_xor(t.w, 32);

    __syncthreads();                       // all A2/A_s reads done; st_f reusable
    if (lane < 16)
        ((float4*)st_f)[w * 16 + o4] = t;  // red[w][64] overlay on st_f
    __syncthreads();

    // ------- Output: combine wave-pair halves, normalize, bias, ReLU -------
    if (tid < G * 64) {
        const int go = tid >> 6;   // 0..3
        const int oo = tid & 63;
        const int row = g0 + go;
        if (row < n_out) {
            const float s = st_f[(2 * go) * 64 + oo] + st_f[(2 * go + 1) * 64 + oo];
            float d = den_s[go];
            d = (d != 0.f) ? d : 1.f;
            out[row * 64 + oo] = fmaxf(s / d + bias[oo], 0.f);
        }
    }
}

extern "C" void kernel_launch(void* const* d_in, const int* in_sizes, int n_in,
                              void* d_out, int out_size, void* d_ws, size_t ws_size,
                              hipStream_t stream) {
    const float* feats        = (const float*)d_in[0];
    const float* inp_points   = (const float*)d_in[1];
    const float* out_points   = (const float*)d_in[2];
    const float* out_extents  = (const float*)d_in[3];
    const float* scale_compat = (const float*)d_in[4];
    const int*   nbr_index    = (const int*)d_in[5];
    const int*   row_splits   = (const int*)d_in[6];
    const float* nbr_dist     = (const float*)d_in[7];
    const float* Wmat         = (const float*)d_in[8];
    const float* bias         = (const float*)d_in[9];
    float*       out          = (float*)d_out;

    const int n_out = in_sizes[2] / 3;
    if (n_out <= 0) return;
    const int nwg = (n_out + G - 1) / G;

    hipLaunchKernelGGL(cconv_kern, dim3(nwg), dim3(THREADS), 0, stream,
                       feats, inp_points, out_points, out_extents, scale_compat,
                       nbr_index, row_splits, nbr_dist, Wmat, bias, out, n_out);
}